// Round 1
// baseline (447.395 us; speedup 1.0000x reference)
//
#include <hip/hip_runtime.h>
#include <math.h>

#define D_G 5
#define N_G 100
#define IN_DIM 768
#define T_ROWS 100000
#define LN_EPS 1e-5f

// ---------------------------------------------------------------------------
// Kernel A: per-gaussian precompute (inverse covariance folded + const term)
// ws layout: coeffs[k][16]: [0..4] diag(Minv), [5..14] 2*Minv[i][j] (i<j),
//            [15] = -0.5*(d*log(2pi) + logdet)
// ---------------------------------------------------------------------------
__global__ void precompute_gauss(const float* __restrict__ cov,
                                 float* __restrict__ coeffs) {
    int k = blockIdx.x * blockDim.x + threadIdx.x;
    if (k >= N_G) return;
    double a[D_G][D_G], inv[D_G][D_G];
    for (int i = 0; i < D_G; ++i)
        for (int j = 0; j < D_G; ++j) {
            a[i][j] = (double)cov[(k * D_G + i) * D_G + j];
            inv[i][j] = (i == j) ? 1.0 : 0.0;
        }
    double det = 1.0;
    for (int c = 0; c < D_G; ++c) {
        int p = c;
        double best = fabs(a[c][c]);
        for (int r = c + 1; r < D_G; ++r) {
            double v = fabs(a[r][c]);
            if (v > best) { best = v; p = r; }
        }
        if (p != c) {
            for (int j = 0; j < D_G; ++j) {
                double t = a[c][j]; a[c][j] = a[p][j]; a[p][j] = t;
                t = inv[c][j]; inv[c][j] = inv[p][j]; inv[p][j] = t;
            }
        }
        double piv = a[c][c];
        det *= piv;
        double ip = 1.0 / piv;
        for (int j = 0; j < D_G; ++j) { a[c][j] *= ip; inv[c][j] *= ip; }
        for (int r = 0; r < D_G; ++r) {
            if (r == c) continue;
            double f = a[r][c];
            if (f != 0.0)
                for (int j = 0; j < D_G; ++j) {
                    a[r][j] -= f * a[c][j];
                    inv[r][j] -= f * inv[c][j];
                }
        }
    }
    double logdet = log(fabs(det));
    float* o = coeffs + k * 16;
    for (int i = 0; i < D_G; ++i) o[i] = (float)inv[i][i];
    int idx = D_G;
    for (int i = 0; i < D_G; ++i)
        for (int j = i + 1; j < D_G; ++j) o[idx++] = (float)(2.0 * inv[i][j]);
    o[15] = (float)(-0.5 * ((double)D_G * log(2.0 * 3.14159265358979323846) + logdet));
}

// ---------------------------------------------------------------------------
// Gaussian eval with folded symmetric coefficients
// ---------------------------------------------------------------------------
__device__ __forceinline__ float gm_eval(const float z[D_G], const float* ct,
                                         const float* cf, float cc) {
    float d0 = z[0] - ct[0];
    float d1 = z[1] - ct[1];
    float d2 = z[2] - ct[2];
    float d3 = z[3] - ct[3];
    float d4 = z[4] - ct[4];
    float m = cf[0] * (d0 * d0);
    m = fmaf(cf[1], d1 * d1, m);
    m = fmaf(cf[2], d2 * d2, m);
    m = fmaf(cf[3], d3 * d3, m);
    m = fmaf(cf[4], d4 * d4, m);
    m = fmaf(cf[5], d0 * d1, m);
    m = fmaf(cf[6], d0 * d2, m);
    m = fmaf(cf[7], d0 * d3, m);
    m = fmaf(cf[8], d0 * d4, m);
    m = fmaf(cf[9], d1 * d2, m);
    m = fmaf(cf[10], d1 * d3, m);
    m = fmaf(cf[11], d1 * d4, m);
    m = fmaf(cf[12], d2 * d3, m);
    m = fmaf(cf[13], d2 * d4, m);
    m = fmaf(cf[14], d3 * d4, m);
    return __expf(fmaf(-0.5f, m, cc));
}

// ---------------------------------------------------------------------------
// Kernel B: main. One wave (64 lanes) per row, grid-stride over T rows.
// Lane l owns columns {l*4 + i*256 + q}, i in 0..2, q in 0..3 (coalesced
// float4: 64 lanes x 16B = 1KB per load instruction). W held in registers.
// ---------------------------------------------------------------------------
__launch_bounds__(256)
__global__ void gm_main(const float* __restrict__ x, const float* __restrict__ W,
                        const float* __restrict__ bb,
                        const float* __restrict__ centers,
                        const float* __restrict__ gamma_,
                        const float* __restrict__ beta_,
                        const float* __restrict__ coeffs,
                        float* __restrict__ partials, int nblk) {
    const int lane = threadIdx.x & 63;
    const int wid = threadIdx.x >> 6;
    const int gw = blockIdx.x * 4 + wid;
    const int nw = nblk * 4;

    // W in registers: wreg[j][i] = W[j*768 + i*256 + lane*4 .. +3]
    float4 wreg[D_G][3];
#pragma unroll
    for (int j = 0; j < D_G; ++j)
#pragma unroll
        for (int i = 0; i < 3; ++i)
            wreg[j][i] = *reinterpret_cast<const float4*>(W + j * IN_DIM + i * 256 + lane * 4);

    float bj[D_G];
#pragma unroll
    for (int j = 0; j < D_G; ++j) bj[j] = bb[j];

    const int k0 = lane;                   // gaussians 0..63
    const bool has1 = lane < (N_G - 64);   // lanes 0..35 also own 64..99
    const int k1 = has1 ? (64 + lane) : lane;

    float cf0[15], cf1[15], ct0[D_G], ct1[D_G];
#pragma unroll
    for (int i = 0; i < 15; ++i) { cf0[i] = coeffs[k0 * 16 + i]; cf1[i] = coeffs[k1 * 16 + i]; }
#pragma unroll
    for (int i = 0; i < D_G; ++i) { ct0[i] = centers[k0 * D_G + i]; ct1[i] = centers[k1 * D_G + i]; }
    const float cc0 = coeffs[k0 * 16 + 15], cc1 = coeffs[k1 * 16 + 15];
    const float g0 = gamma_[k0], g1 = gamma_[k1];
    const float be0 = beta_[k0], be1 = beta_[k1];

    float acc0 = 0.f, acc1 = 0.f;

    for (int t = gw; t < T_ROWS; t += nw) {
        const float* xr = x + (size_t)t * IN_DIM;
        const float4 xv0 = *reinterpret_cast<const float4*>(xr + lane * 4);
        const float4 xv1 = *reinterpret_cast<const float4*>(xr + 256 + lane * 4);
        const float4 xv2 = *reinterpret_cast<const float4*>(xr + 512 + lane * 4);

        float p[D_G];
#pragma unroll
        for (int j = 0; j < D_G; ++j) {
            const float4 w0 = wreg[j][0], w1 = wreg[j][1], w2 = wreg[j][2];
            float s = xv0.x * w0.x;
            s = fmaf(xv0.y, w0.y, s);
            s = fmaf(xv0.z, w0.z, s);
            s = fmaf(xv0.w, w0.w, s);
            s = fmaf(xv1.x, w1.x, s);
            s = fmaf(xv1.y, w1.y, s);
            s = fmaf(xv1.z, w1.z, s);
            s = fmaf(xv1.w, w1.w, s);
            s = fmaf(xv2.x, w2.x, s);
            s = fmaf(xv2.y, w2.y, s);
            s = fmaf(xv2.z, w2.z, s);
            s = fmaf(xv2.w, w2.w, s);
            p[j] = s;
        }
        // wave-wide butterfly reduce each partial (all lanes end with the sum)
#pragma unroll
        for (int j = 0; j < D_G; ++j) {
#pragma unroll
            for (int m = 32; m >= 1; m >>= 1) p[j] += __shfl_xor(p[j], m, 64);
        }
        float z[D_G];
#pragma unroll
        for (int j = 0; j < D_G; ++j)
            z[j] = 1.0f / (1.0f + __expf(-(p[j] + bj[j])));

        const float lik0 = gm_eval(z, ct0, cf0, cc0);
        const float lik1 = has1 ? gm_eval(z, ct1, cf1, cc1) : 0.f;

        float s = lik0 + lik1;
        float q = fmaf(lik0, lik0, lik1 * lik1);
#pragma unroll
        for (int m = 32; m >= 1; m >>= 1) {
            s += __shfl_xor(s, m, 64);
            q += __shfl_xor(q, m, 64);
        }
        const float mu = s * (1.0f / N_G);
        float var = fmaf(q, 1.0f / N_G, -mu * mu);
        var = fmaxf(var, 0.f);
        const float r = rsqrtf(var + LN_EPS);
        acc0 += fmaf((lik0 - mu) * r, g0, be0);
        if (has1) acc1 += fmaf((lik1 - mu) * r, g1, be1);
    }

    __shared__ float sacc[N_G];
    if (threadIdx.x < N_G) sacc[threadIdx.x] = 0.f;
    __syncthreads();
    atomicAdd(&sacc[k0], acc0);
    if (has1) atomicAdd(&sacc[k1], acc1);
    __syncthreads();
    if (threadIdx.x < N_G)
        partials[(size_t)threadIdx.x * nblk + blockIdx.x] = sacc[threadIdx.x];
}

// ---------------------------------------------------------------------------
// Kernel C: reduce per-block partials -> out[k] (double accumulation)
// ---------------------------------------------------------------------------
__global__ void reduce_partials(const float* __restrict__ partials,
                                float* __restrict__ out, int nblk) {
    const int k = blockIdx.x;
    const int lane = threadIdx.x & 63;
    const int wid = threadIdx.x >> 6;
    double d = 0.0;
    for (int b = threadIdx.x; b < nblk; b += blockDim.x)
        d += (double)partials[(size_t)k * nblk + b];
#pragma unroll
    for (int m = 32; m >= 1; m >>= 1) d += __shfl_xor(d, m, 64);
    __shared__ double sd[4];
    if (lane == 0) sd[wid] = d;
    __syncthreads();
    if (threadIdx.x == 0)
        out[k] = (float)((sd[0] + sd[1] + sd[2] + sd[3]) * (1.0 / (double)T_ROWS));
}

extern "C" void kernel_launch(void* const* d_in, const int* in_sizes, int n_in,
                              void* d_out, int out_size, void* d_ws, size_t ws_size,
                              hipStream_t stream) {
    const float* x = (const float*)d_in[0];
    const float* W = (const float*)d_in[1];
    const float* b = (const float*)d_in[2];
    const float* centers = (const float*)d_in[3];
    const float* cov = (const float*)d_in[4];
    const float* gamma_ = (const float*)d_in[5];
    const float* beta_ = (const float*)d_in[6];
    float* out = (float*)d_out;

    float* ws = (float*)d_ws;
    float* coeffs = ws;                 // N_G * 16 floats
    float* partials = ws + N_G * 16;    // nblk * N_G floats

    int nblk = 1024;
    {
        long avail = (long)(ws_size / sizeof(float)) - (long)(N_G * 16);
        long maxblk = avail / N_G;
        if (maxblk < nblk) nblk = (int)maxblk;
        if (nblk < 1) nblk = 1;
    }

    precompute_gauss<<<1, 128, 0, stream>>>(cov, coeffs);
    gm_main<<<nblk, 256, 0, stream>>>(x, W, b, centers, gamma_, beta_, coeffs,
                                      partials, nblk);
    reduce_partials<<<N_G, 256, 0, stream>>>(partials, out, nblk);
}

// Round 2
// 438.781 us; speedup vs baseline: 1.0196x; 1.0196x over previous
//
#include <hip/hip_runtime.h>
#include <math.h>

#define D_G 5
#define N_G 100
#define IN_DIM 768
#define T_ROWS 100000
#define LN_EPS 1e-5f

// ---------------------------------------------------------------------------
// Kernel A: per-gaussian precompute (inverse covariance folded + const term)
// ws layout: coeffs[k][16]: [0..4] diag(Minv), [5..14] 2*Minv[i][j] (i<j),
//            [15] = -0.5*(d*log(2pi) + logdet)
// ---------------------------------------------------------------------------
__global__ void precompute_gauss(const float* __restrict__ cov,
                                 float* __restrict__ coeffs) {
    int k = blockIdx.x * blockDim.x + threadIdx.x;
    if (k >= N_G) return;
    double a[D_G][D_G], inv[D_G][D_G];
    for (int i = 0; i < D_G; ++i)
        for (int j = 0; j < D_G; ++j) {
            a[i][j] = (double)cov[(k * D_G + i) * D_G + j];
            inv[i][j] = (i == j) ? 1.0 : 0.0;
        }
    double det = 1.0;
    for (int c = 0; c < D_G; ++c) {
        int p = c;
        double best = fabs(a[c][c]);
        for (int r = c + 1; r < D_G; ++r) {
            double v = fabs(a[r][c]);
            if (v > best) { best = v; p = r; }
        }
        if (p != c) {
            for (int j = 0; j < D_G; ++j) {
                double t = a[c][j]; a[c][j] = a[p][j]; a[p][j] = t;
                t = inv[c][j]; inv[c][j] = inv[p][j]; inv[p][j] = t;
            }
            det = -det;
        }
        double piv = a[c][c];
        det *= piv;
        double ip = 1.0 / piv;
        for (int j = 0; j < D_G; ++j) { a[c][j] *= ip; inv[c][j] *= ip; }
        for (int r = 0; r < D_G; ++r) {
            if (r == c) continue;
            double f = a[r][c];
            if (f != 0.0)
                for (int j = 0; j < D_G; ++j) {
                    a[r][j] -= f * a[c][j];
                    inv[r][j] -= f * inv[c][j];
                }
        }
    }
    double logdet = log(fabs(det));
    float* o = coeffs + k * 16;
    for (int i = 0; i < D_G; ++i) o[i] = (float)inv[i][i];
    int idx = D_G;
    for (int i = 0; i < D_G; ++i)
        for (int j = i + 1; j < D_G; ++j) o[idx++] = (float)(2.0 * inv[i][j]);
    o[15] = (float)(-0.5 * ((double)D_G * log(2.0 * 3.14159265358979323846) + logdet));
}

// ---------------------------------------------------------------------------
// Gaussian eval with folded symmetric coefficients
// ---------------------------------------------------------------------------
__device__ __forceinline__ float gm_eval(const float z[D_G], const float* ct,
                                         const float* cf, float cc) {
    float d0 = z[0] - ct[0];
    float d1 = z[1] - ct[1];
    float d2 = z[2] - ct[2];
    float d3 = z[3] - ct[3];
    float d4 = z[4] - ct[4];
    float m = cf[0] * (d0 * d0);
    m = fmaf(cf[1], d1 * d1, m);
    m = fmaf(cf[2], d2 * d2, m);
    m = fmaf(cf[3], d3 * d3, m);
    m = fmaf(cf[4], d4 * d4, m);
    m = fmaf(cf[5], d0 * d1, m);
    m = fmaf(cf[6], d0 * d2, m);
    m = fmaf(cf[7], d0 * d3, m);
    m = fmaf(cf[8], d0 * d4, m);
    m = fmaf(cf[9], d1 * d2, m);
    m = fmaf(cf[10], d1 * d3, m);
    m = fmaf(cf[11], d1 * d4, m);
    m = fmaf(cf[12], d2 * d3, m);
    m = fmaf(cf[13], d2 * d4, m);
    m = fmaf(cf[14], d3 * d4, m);
    return __expf(fmaf(-0.5f, m, cc));
}

// ---------------------------------------------------------------------------
// Kernel B: main. One wave (64 lanes) per row, grid-stride over T rows.
// Explicit double-buffer prefetch of the next row hides HBM latency behind
// the shuffle/exp chain. Accumulates S_k = sum_t lik_k*r_t and A = sum_t
// mu_t*r_t; gamma/beta and the (S_k - A)/T are applied in the reduce kernel
// (better cancellation: done in double).
// ---------------------------------------------------------------------------
__launch_bounds__(256)
__global__ void gm_main(const float* __restrict__ x, const float* __restrict__ W,
                        const float* __restrict__ bb,
                        const float* __restrict__ centers,
                        const float* __restrict__ coeffs,
                        float* __restrict__ partials, int nblk) {
    const int lane = threadIdx.x & 63;
    const int wid = threadIdx.x >> 6;
    const int gw = blockIdx.x * 4 + wid;
    const int nw = nblk * 4;

    // W in registers: wreg[j][i] = W[j*768 + i*256 + lane*4 .. +3]
    float4 wreg[D_G][3];
#pragma unroll
    for (int j = 0; j < D_G; ++j)
#pragma unroll
        for (int i = 0; i < 3; ++i)
            wreg[j][i] = *reinterpret_cast<const float4*>(W + j * IN_DIM + i * 256 + lane * 4);

    float bj[D_G];
#pragma unroll
    for (int j = 0; j < D_G; ++j) bj[j] = bb[j];

    const int k0 = lane;                   // gaussians 0..63
    const bool has1 = lane < (N_G - 64);   // lanes 0..35 also own 64..99
    const int k1 = has1 ? (64 + lane) : lane;

    float cf0[15], cf1[15], ct0[D_G], ct1[D_G];
#pragma unroll
    for (int i = 0; i < 15; ++i) { cf0[i] = coeffs[k0 * 16 + i]; cf1[i] = coeffs[k1 * 16 + i]; }
#pragma unroll
    for (int i = 0; i < D_G; ++i) { ct0[i] = centers[k0 * D_G + i]; ct1[i] = centers[k1 * D_G + i]; }
    const float cc0 = coeffs[k0 * 16 + 15], cc1 = coeffs[k1 * 16 + 15];

    float acc0 = 0.f, acc1 = 0.f, accA = 0.f;

    int t = gw;
    float4 a0{}, a1{}, a2{};
    if (t < T_ROWS) {
        const float* xr = x + (size_t)t * IN_DIM + lane * 4;
        a0 = *reinterpret_cast<const float4*>(xr);
        a1 = *reinterpret_cast<const float4*>(xr + 256);
        a2 = *reinterpret_cast<const float4*>(xr + 512);
    }

    while (t < T_ROWS) {
        const int tn = t + nw;
        float4 b0{}, b1{}, b2{};
        if (tn < T_ROWS) {  // prefetch next row before the long dependency chain
            const float* xr = x + (size_t)tn * IN_DIM + lane * 4;
            b0 = *reinterpret_cast<const float4*>(xr);
            b1 = *reinterpret_cast<const float4*>(xr + 256);
            b2 = *reinterpret_cast<const float4*>(xr + 512);
        }

        float p[D_G];
#pragma unroll
        for (int j = 0; j < D_G; ++j) {
            const float4 w0 = wreg[j][0], w1 = wreg[j][1], w2 = wreg[j][2];
            float s = a0.x * w0.x;
            s = fmaf(a0.y, w0.y, s);
            s = fmaf(a0.z, w0.z, s);
            s = fmaf(a0.w, w0.w, s);
            s = fmaf(a1.x, w1.x, s);
            s = fmaf(a1.y, w1.y, s);
            s = fmaf(a1.z, w1.z, s);
            s = fmaf(a1.w, w1.w, s);
            s = fmaf(a2.x, w2.x, s);
            s = fmaf(a2.y, w2.y, s);
            s = fmaf(a2.z, w2.z, s);
            s = fmaf(a2.w, w2.w, s);
            p[j] = s;
        }
        // wave-wide butterfly reduce each partial (all lanes end with the sum)
#pragma unroll
        for (int j = 0; j < D_G; ++j) {
#pragma unroll
            for (int m = 32; m >= 1; m >>= 1) p[j] += __shfl_xor(p[j], m, 64);
        }
        float z[D_G];
#pragma unroll
        for (int j = 0; j < D_G; ++j)
            z[j] = 1.0f / (1.0f + __expf(-(p[j] + bj[j])));

        const float lik0 = gm_eval(z, ct0, cf0, cc0);
        const float lik1 = has1 ? gm_eval(z, ct1, cf1, cc1) : 0.f;

        float s = lik0 + lik1;
        float q = fmaf(lik0, lik0, lik1 * lik1);
#pragma unroll
        for (int m = 32; m >= 1; m >>= 1) {
            s += __shfl_xor(s, m, 64);
            q += __shfl_xor(q, m, 64);
        }
        const float mu = s * (1.0f / N_G);
        float var = fmaf(q, 1.0f / N_G, -mu * mu);
        var = fmaxf(var, 0.f);
        const float r = rsqrtf(var + LN_EPS);
        acc0 = fmaf(lik0, r, acc0);
        if (has1) acc1 = fmaf(lik1, r, acc1);
        accA = fmaf(mu, r, accA);

        a0 = b0; a1 = b1; a2 = b2;
        t = tn;
    }

    __shared__ float sacc[N_G + 1];
    if (threadIdx.x < N_G + 1) sacc[threadIdx.x] = 0.f;
    __syncthreads();
    atomicAdd(&sacc[k0], acc0);
    if (has1) atomicAdd(&sacc[k1], acc1);
    if (lane == 0) atomicAdd(&sacc[N_G], accA);
    __syncthreads();
    if (threadIdx.x < N_G + 1)
        partials[(size_t)threadIdx.x * nblk + blockIdx.x] = sacc[threadIdx.x];
}

// ---------------------------------------------------------------------------
// Kernel C: reduce per-block partials -> out[k] (double accumulation),
// applying LayerNorm affine: out_k = gamma_k*(S_k - A)/T + beta_k
// ---------------------------------------------------------------------------
__global__ void reduce_partials(const float* __restrict__ partials,
                                const float* __restrict__ gamma_,
                                const float* __restrict__ beta_,
                                float* __restrict__ out, int nblk) {
    const int k = blockIdx.x;
    const int lane = threadIdx.x & 63;
    const int wid = threadIdx.x >> 6;
    double dk = 0.0, dA = 0.0;
    for (int b = threadIdx.x; b < nblk; b += blockDim.x) {
        dk += (double)partials[(size_t)k * nblk + b];
        dA += (double)partials[(size_t)N_G * nblk + b];
    }
#pragma unroll
    for (int m = 32; m >= 1; m >>= 1) {
        dk += __shfl_xor(dk, m, 64);
        dA += __shfl_xor(dA, m, 64);
    }
    __shared__ double sk[4], sA[4];
    if (lane == 0) { sk[wid] = dk; sA[wid] = dA; }
    __syncthreads();
    if (threadIdx.x == 0) {
        double S = sk[0] + sk[1] + sk[2] + sk[3];
        double A = sA[0] + sA[1] + sA[2] + sA[3];
        out[k] = (float)((double)gamma_[k] * (S - A) * (1.0 / (double)T_ROWS)
                         + (double)beta_[k]);
    }
}

extern "C" void kernel_launch(void* const* d_in, const int* in_sizes, int n_in,
                              void* d_out, int out_size, void* d_ws, size_t ws_size,
                              hipStream_t stream) {
    const float* x = (const float*)d_in[0];
    const float* W = (const float*)d_in[1];
    const float* b = (const float*)d_in[2];
    const float* centers = (const float*)d_in[3];
    const float* cov = (const float*)d_in[4];
    const float* gamma_ = (const float*)d_in[5];
    const float* beta_ = (const float*)d_in[6];
    float* out = (float*)d_out;

    float* ws = (float*)d_ws;
    float* coeffs = ws;                 // N_G * 16 floats
    float* partials = ws + N_G * 16;    // (N_G+1) * nblk floats

    int nblk = 1024;
    {
        long avail = (long)(ws_size / sizeof(float)) - (long)(N_G * 16);
        long maxblk = avail / (N_G + 1);
        if (maxblk < nblk) nblk = (int)maxblk;
        if (nblk < 1) nblk = 1;
    }

    precompute_gauss<<<1, 128, 0, stream>>>(cov, coeffs);
    gm_main<<<nblk, 256, 0, stream>>>(x, W, b, centers, coeffs, partials, nblk);
    reduce_partials<<<N_G, 256, 0, stream>>>(partials, gamma_, beta_, out, nblk);
}

// Round 3
// 432.842 us; speedup vs baseline: 1.0336x; 1.0137x over previous
//
#include <hip/hip_runtime.h>
#include <math.h>

#define D_G 5
#define N_G 100
#define IN_DIM 768
#define T_ROWS 100000
#define LN_EPS 1e-5f

// ---------------------------------------------------------------------------
// Kernel A: per-gaussian precompute (inverse covariance folded + const term)
// ws layout: coeffs[k][16]: [0..4] diag(Minv), [5..14] 2*Minv[i][j] (i<j),
//            [15] = -0.5*(d*log(2pi) + logdet)
// ---------------------------------------------------------------------------
__global__ void precompute_gauss(const float* __restrict__ cov,
                                 float* __restrict__ coeffs) {
    int k = blockIdx.x * blockDim.x + threadIdx.x;
    if (k >= N_G) return;
    double a[D_G][D_G], inv[D_G][D_G];
    for (int i = 0; i < D_G; ++i)
        for (int j = 0; j < D_G; ++j) {
            a[i][j] = (double)cov[(k * D_G + i) * D_G + j];
            inv[i][j] = (i == j) ? 1.0 : 0.0;
        }
    double det = 1.0;
    for (int c = 0; c < D_G; ++c) {
        int p = c;
        double best = fabs(a[c][c]);
        for (int r = c + 1; r < D_G; ++r) {
            double v = fabs(a[r][c]);
            if (v > best) { best = v; p = r; }
        }
        if (p != c) {
            for (int j = 0; j < D_G; ++j) {
                double t = a[c][j]; a[c][j] = a[p][j]; a[p][j] = t;
                t = inv[c][j]; inv[c][j] = inv[p][j]; inv[p][j] = t;
            }
            det = -det;
        }
        double piv = a[c][c];
        det *= piv;
        double ip = 1.0 / piv;
        for (int j = 0; j < D_G; ++j) { a[c][j] *= ip; inv[c][j] *= ip; }
        for (int r = 0; r < D_G; ++r) {
            if (r == c) continue;
            double f = a[r][c];
            if (f != 0.0)
                for (int j = 0; j < D_G; ++j) {
                    a[r][j] -= f * a[c][j];
                    inv[r][j] -= f * inv[c][j];
                }
        }
    }
    double logdet = log(fabs(det));
    float* o = coeffs + k * 16;
    for (int i = 0; i < D_G; ++i) o[i] = (float)inv[i][i];
    int idx = D_G;
    for (int i = 0; i < D_G; ++i)
        for (int j = i + 1; j < D_G; ++j) o[idx++] = (float)(2.0 * inv[i][j]);
    o[15] = (float)(-0.5 * ((double)D_G * log(2.0 * 3.14159265358979323846) + logdet));
}

// ---------------------------------------------------------------------------
// Gaussian eval with folded symmetric coefficients
// ---------------------------------------------------------------------------
__device__ __forceinline__ float gm_eval(const float z[D_G], const float* ct,
                                         const float* cf, float cc) {
    float d0 = z[0] - ct[0];
    float d1 = z[1] - ct[1];
    float d2 = z[2] - ct[2];
    float d3 = z[3] - ct[3];
    float d4 = z[4] - ct[4];
    float m = cf[0] * (d0 * d0);
    m = fmaf(cf[1], d1 * d1, m);
    m = fmaf(cf[2], d2 * d2, m);
    m = fmaf(cf[3], d3 * d3, m);
    m = fmaf(cf[4], d4 * d4, m);
    m = fmaf(cf[5], d0 * d1, m);
    m = fmaf(cf[6], d0 * d2, m);
    m = fmaf(cf[7], d0 * d3, m);
    m = fmaf(cf[8], d0 * d4, m);
    m = fmaf(cf[9], d1 * d2, m);
    m = fmaf(cf[10], d1 * d3, m);
    m = fmaf(cf[11], d1 * d4, m);
    m = fmaf(cf[12], d2 * d3, m);
    m = fmaf(cf[13], d2 * d4, m);
    m = fmaf(cf[14], d3 * d4, m);
    return __expf(fmaf(-0.5f, m, cc));
}

// ---------------------------------------------------------------------------
// Kernel B: main. One wave (64 lanes) per row, grid-stride over T rows.
// Explicit double-buffer prefetch hides HBM latency behind the shuffle/exp
// chain. v_rcp_f32 sigmoid (1-instr reciprocal), branchless 2nd gaussian.
// Accumulates S_k = sum lik_k*r and A = sum mu*r; affine applied in reduce.
// ---------------------------------------------------------------------------
__launch_bounds__(256)
__global__ void gm_main(const float* __restrict__ x, const float* __restrict__ W,
                        const float* __restrict__ bb,
                        const float* __restrict__ centers,
                        const float* __restrict__ coeffs,
                        float* __restrict__ partials, int nblk) {
    const int lane = threadIdx.x & 63;
    const int wid = threadIdx.x >> 6;
    const int gw = blockIdx.x * 4 + wid;
    const int nw = nblk * 4;

    // W in registers: wreg[j][i] = W[j*768 + i*256 + lane*4 .. +3]
    float4 wreg[D_G][3];
#pragma unroll
    for (int j = 0; j < D_G; ++j)
#pragma unroll
        for (int i = 0; i < 3; ++i)
            wreg[j][i] = *reinterpret_cast<const float4*>(W + j * IN_DIM + i * 256 + lane * 4);

    float bj[D_G];
#pragma unroll
    for (int j = 0; j < D_G; ++j) bj[j] = bb[j];

    const int k0 = lane;                   // gaussians 0..63
    const bool has1 = lane < (N_G - 64);   // lanes 0..35 also own 64..99
    const int k1 = has1 ? (64 + lane) : lane;

    float cf0[15], cf1[15], ct0[D_G], ct1[D_G];
#pragma unroll
    for (int i = 0; i < 15; ++i) { cf0[i] = coeffs[k0 * 16 + i]; cf1[i] = coeffs[k1 * 16 + i]; }
#pragma unroll
    for (int i = 0; i < D_G; ++i) { ct0[i] = centers[k0 * D_G + i]; ct1[i] = centers[k1 * D_G + i]; }
    const float cc0 = coeffs[k0 * 16 + 15], cc1 = coeffs[k1 * 16 + 15];

    float acc0 = 0.f, acc1 = 0.f, accA = 0.f;

    int t = gw;
    float4 a0{}, a1{}, a2{};
    if (t < T_ROWS) {
        const float* xr = x + (size_t)t * IN_DIM + lane * 4;
        a0 = *reinterpret_cast<const float4*>(xr);
        a1 = *reinterpret_cast<const float4*>(xr + 256);
        a2 = *reinterpret_cast<const float4*>(xr + 512);
    }

    while (t < T_ROWS) {
        const int tn = t + nw;
        float4 b0{}, b1{}, b2{};
        if (tn < T_ROWS) {  // prefetch next row before the long dependency chain
            const float* xr = x + (size_t)tn * IN_DIM + lane * 4;
            b0 = *reinterpret_cast<const float4*>(xr);
            b1 = *reinterpret_cast<const float4*>(xr + 256);
            b2 = *reinterpret_cast<const float4*>(xr + 512);
        }

        float p[D_G];
#pragma unroll
        for (int j = 0; j < D_G; ++j) {
            const float4 w0 = wreg[j][0], w1 = wreg[j][1], w2 = wreg[j][2];
            float s = a0.x * w0.x;
            s = fmaf(a0.y, w0.y, s);
            s = fmaf(a0.z, w0.z, s);
            s = fmaf(a0.w, w0.w, s);
            s = fmaf(a1.x, w1.x, s);
            s = fmaf(a1.y, w1.y, s);
            s = fmaf(a1.z, w1.z, s);
            s = fmaf(a1.w, w1.w, s);
            s = fmaf(a2.x, w2.x, s);
            s = fmaf(a2.y, w2.y, s);
            s = fmaf(a2.z, w2.z, s);
            s = fmaf(a2.w, w2.w, s);
            p[j] = s;
        }
        // wave-wide butterfly reduce each partial (all lanes end with the sum)
#pragma unroll
        for (int j = 0; j < D_G; ++j) {
#pragma unroll
            for (int m = 32; m >= 1; m >>= 1) p[j] += __shfl_xor(p[j], m, 64);
        }
        float z[D_G];
#pragma unroll
        for (int j = 0; j < D_G; ++j)
            z[j] = __builtin_amdgcn_rcpf(1.0f + __expf(-(p[j] + bj[j])));

        const float lik0 = gm_eval(z, ct0, cf0, cc0);
        // coefficients for lanes >= 36 alias k0, so the eval is valid for all
        // lanes; mask the result instead of branching (no half-wave divergence)
        const float e1 = gm_eval(z, ct1, cf1, cc1);
        const float lik1 = has1 ? e1 : 0.f;

        float s = lik0 + lik1;
        float q = fmaf(lik0, lik0, lik1 * lik1);
#pragma unroll
        for (int m = 32; m >= 1; m >>= 1) {
            s += __shfl_xor(s, m, 64);
            q += __shfl_xor(q, m, 64);
        }
        const float mu = s * (1.0f / N_G);
        float var = fmaf(q, 1.0f / N_G, -mu * mu);
        var = fmaxf(var, 0.f);
        const float r = rsqrtf(var + LN_EPS);
        acc0 = fmaf(lik0, r, acc0);
        acc1 = fmaf(lik1, r, acc1);   // lik1==0 for lanes>=36: harmless
        accA = fmaf(mu, r, accA);

        a0 = b0; a1 = b1; a2 = b2;
        t = tn;
    }

    __shared__ float sacc[N_G + 1];
    if (threadIdx.x < N_G + 1) sacc[threadIdx.x] = 0.f;
    __syncthreads();
    atomicAdd(&sacc[k0], acc0);
    if (has1) atomicAdd(&sacc[k1], acc1);
    if (lane == 0) atomicAdd(&sacc[N_G], accA);
    __syncthreads();
    if (threadIdx.x < N_G + 1)
        partials[(size_t)threadIdx.x * nblk + blockIdx.x] = sacc[threadIdx.x];
}

// ---------------------------------------------------------------------------
// Kernel C: reduce per-block partials -> out[k] (double accumulation),
// applying LayerNorm affine: out_k = gamma_k*(S_k - A)/T + beta_k
// ---------------------------------------------------------------------------
__global__ void reduce_partials(const float* __restrict__ partials,
                                const float* __restrict__ gamma_,
                                const float* __restrict__ beta_,
                                float* __restrict__ out, int nblk) {
    const int k = blockIdx.x;
    const int lane = threadIdx.x & 63;
    const int wid = threadIdx.x >> 6;
    double dk = 0.0, dA = 0.0;
    for (int b = threadIdx.x; b < nblk; b += blockDim.x) {
        dk += (double)partials[(size_t)k * nblk + b];
        dA += (double)partials[(size_t)N_G * nblk + b];
    }
#pragma unroll
    for (int m = 32; m >= 1; m >>= 1) {
        dk += __shfl_xor(dk, m, 64);
        dA += __shfl_xor(dA, m, 64);
    }
    __shared__ double sk[4], sA[4];
    if (lane == 0) { sk[wid] = dk; sA[wid] = dA; }
    __syncthreads();
    if (threadIdx.x == 0) {
        double S = sk[0] + sk[1] + sk[2] + sk[3];
        double A = sA[0] + sA[1] + sA[2] + sA[3];
        out[k] = (float)((double)gamma_[k] * (S - A) * (1.0 / (double)T_ROWS)
                         + (double)beta_[k]);
    }
}

extern "C" void kernel_launch(void* const* d_in, const int* in_sizes, int n_in,
                              void* d_out, int out_size, void* d_ws, size_t ws_size,
                              hipStream_t stream) {
    const float* x = (const float*)d_in[0];
    const float* W = (const float*)d_in[1];
    const float* b = (const float*)d_in[2];
    const float* centers = (const float*)d_in[3];
    const float* cov = (const float*)d_in[4];
    const float* gamma_ = (const float*)d_in[5];
    const float* beta_ = (const float*)d_in[6];
    float* out = (float*)d_out;

    float* ws = (float*)d_ws;
    float* coeffs = ws;                 // N_G * 16 floats
    float* partials = ws + N_G * 16;    // (N_G+1) * nblk floats

    // 768 blocks = 3 blocks/CU resident on 256 CUs -> no scheduling tail
    int nblk = 768;
    {
        long avail = (long)(ws_size / sizeof(float)) - (long)(N_G * 16);
        long maxblk = avail / (N_G + 1);
        if (maxblk < nblk) nblk = (int)maxblk;
        if (nblk < 1) nblk = 1;
    }

    precompute_gauss<<<1, 128, 0, stream>>>(cov, coeffs);
    gm_main<<<nblk, 256, 0, stream>>>(x, W, b, centers, coeffs, partials, nblk);
    reduce_partials<<<N_G, 256, 0, stream>>>(partials, gamma_, beta_, out, nblk);
}